// Round 10
// baseline (392.374 us; speedup 1.0000x reference)
//
#include <hip/hip_runtime.h>
#include <math.h>

#define LSEQ 2048
#define KNB 64
#define BATCH 8
#define MRBF 7
#define NTILES 8192               // 2 rows per tile, 128 pairs
#define NBLOCKS 512               // 16 tiles per block exactly, 2 blocks/CU
#define BSCALE (255.0f/144.0f)

typedef __attribute__((ext_vector_type(8))) short short8;
typedef __attribute__((ext_vector_type(4))) float floatx4;

// RNE float->bf16 (cold path: weight setup)
__device__ __forceinline__ unsigned short f2bf(float f) {
    unsigned u = __float_as_uint(f);
    u += 0x7fffu + ((u >> 16) & 1u);
    return (unsigned short)(u >> 16);
}
// packed round-half-up bf16x2, 3 ops via v_perm (r4-r9 proven)
__device__ __forceinline__ unsigned pkbf(float a, float b) {
    return __builtin_amdgcn_perm(__float_as_uint(b) + 0x8000u,
                                 __float_as_uint(a) + 0x8000u, 0x07060302u);
}

// ---------------------------------------------------------------------------
// Fused kernel r10: SOFTWARE-PIPELINED fusion. topk(t+1) is sliced into the
// barrier intervals of MLP(t) -- its load/atomic latency hides under MFMA
// phases instead of serializing (r7: topk ~40% of the 29k-cycle tile wall).
// Barriers: 10 -> 5 per tile. nbrL double-buffered; hist dedicated (live
// across GEMM slots); cand aliases Xs (dead after GEMM1, rewritten after J).
// Grid 512 = 2 blocks/CU exact (r9 lesson: don't outrun real residency).
// No launch-bounds reg cap (r4/r5/r8 spill lessons); 2 waves/SIMD -> 256 VGPR
// budget, live-state additions are safe.
// Fragment layouts (r2/r4-r9 HW-verified, absmax=0):
//  A[m][k]: m=lane&15, k=quad*8+j | B[k][n]: n=lane&15, k=quad*8+j
//  D[r][c]: r=quad*4+reg, c=lane&15
// ---------------------------------------------------------------------------
__global__ __launch_bounds__(256) void fused_kernel(
    const float* __restrict__ R, const int* __restrict__ seq,
    const float* __restrict__ emb,
    const float* __restrict__ W1, const float* __restrict__ b1,
    const float* __restrict__ W2, const float* __restrict__ b2,
    const float* __restrict__ W3, const float* __restrict__ b3,
    const float* __restrict__ centers, const float* __restrict__ widths,
    float* __restrict__ out)
{
    __shared__ __align__(16) unsigned short lds[26136];   // 52272 B
    unsigned short* Xs = lds;                 // [0,16384): X tile (128x64 bf16)
    unsigned short* Hs = lds + 8192;          // [16384,49152): H1/H2 (128x128)
    int*      nbrL = (int*)(lds + 24576);     // [49152,50176): 2 x 128 ints
    unsigned* hist = (unsigned*)(lds + 25088);// [50176,52224): 2 x 256 u32
    int*      tctr = (int*)(lds + 26112);     // [52224,52264): 10 ints
    int* sB    = tctr + 0;
    int* sNeed = tctr + 2;
    int* oPos  = tctr + 4;
    int* cCnt  = tctr + 6;
    int* fCnt  = tctr + 8;
    // candidate store aliases Xs bytes [0,2048) (Xs dead after GEMM1; cand
    // written in slot G, read in slot I, Xs next written after barrier J):
    float* cand_d2 = (float*)lds;             // 2 x 128 f32
    int*   cand_j  = (int*)(lds + 512);       // 2 x 128 int
    __shared__ float bacc[BATCH];

    const int tid  = threadIdx.x;
    const int lane = tid & 63;
    const int wv   = tid >> 6;
    const int l15  = lane & 15;
    const int q    = lane >> 4;

    // ---- persistent A-operand weight fragments (wave-sharded neurons) ----
    short8 w1f[2][2], w2f[2][4], w3f[4];
    float b1v[2][4], b2v[2][4];
    #pragma unroll
    for (int mtl = 0; mtl < 2; mtl++) {
        int m = (2*wv + mtl)*16 + l15;
        #pragma unroll
        for (int d = 0; d < 4; d++) {
            b1v[mtl][d] = b1[(2*wv + mtl)*16 + q*4 + d];
            b2v[mtl][d] = b2[(2*wv + mtl)*16 + q*4 + d];
        }
        #pragma unroll
        for (int kt = 0; kt < 2; kt++)
            #pragma unroll
            for (int jj = 0; jj < 8; jj++) {
                int k = kt*32 + q*8 + jj;
                w1f[mtl][kt][jj] = (short)((k < 48) ? f2bf(W1[k*128 + m]) : 0);
            }
        #pragma unroll
        for (int kt = 0; kt < 4; kt++)
            #pragma unroll
            for (int jj = 0; jj < 8; jj++) {
                int k = kt*32 + q*8 + jj;
                w2f[mtl][kt][jj] = (short)f2bf(W2[k*128 + m]);
            }
    }
    #pragma unroll
    for (int kt = 0; kt < 4; kt++)
        #pragma unroll
        for (int jj = 0; jj < 8; jj++) {
            int k = kt*32 + q*8 + jj;
            w3f[kt][jj] = (short)((l15 < MRBF) ? f2bf(W3[k*MRBF + l15]) : 0);
        }
    float b3C[4], cen[4], i2w[4];
    #pragma unroll
    for (int d = 0; d < 4; d++) {
        int rb = q*4 + d;
        bool ok = rb < MRBF;
        b3C[d] = ok ? b3[rb] : 0.f;
        cen[d] = ok ? centers[rb] : 0.f;
        float wd = ok ? widths[rb] : 1.f;
        i2w[d] = 0.5f / (wd*wd);
    }
    if (tid < BATCH) bacc[tid] = 0.f;

    const int pl = tid >> 1, half = tid & 1;
    const int s7p = pl & 7;

    float d2r[2][8];   // pipelined topk state for the NEXT tile

    // =============== PROLOGUE: full topk for tile0 -> nbrL[0] ===============
    {
        const int t0 = blockIdx.x;
        hist[tid] = 0u; hist[tid + 256] = 0u;
        if (tid < 2) { oPos[tid] = 0; cCnt[tid] = 0; fCnt[tid] = 0; }
        __syncthreads();
        const int ibn = (t0 & 1023) << 1;
        const float* Rbn = R + (((t0 >> 10) << 11) * 3);
        const float4* rp = (const float4*)(Rbn + tid*24);
        float4 f0=rp[0], f1=rp[1], f2=rp[2], f3=rp[3], f4=rp[4], f5=rp[5];
        float cx0 = Rbn[3*ibn+0], cy0 = Rbn[3*ibn+1], cz0 = Rbn[3*ibn+2];
        float cx1 = Rbn[3*ibn+3], cy1 = Rbn[3*ibn+4], cz1 = Rbn[3*ibn+5];
        float px[8], py[8], pz[8];
        px[0]=f0.x; py[0]=f0.y; pz[0]=f0.z;  px[1]=f0.w; py[1]=f1.x; pz[1]=f1.y;
        px[2]=f1.z; py[2]=f1.w; pz[2]=f2.x;  px[3]=f2.y; py[3]=f2.z; pz[3]=f2.w;
        px[4]=f3.x; py[4]=f3.y; pz[4]=f3.z;  px[5]=f3.w; py[5]=f4.x; pz[5]=f4.y;
        px[6]=f4.z; py[6]=f4.w; pz[6]=f5.x;  px[7]=f5.y; py[7]=f5.z; pz[7]=f5.w;
        #pragma unroll
        for (int u = 0; u < 8; u++) {
            int j = tid*8 + u;
            #pragma unroll
            for (int c = 0; c < 2; c++) {
                float dx = (c ? cx1 : cx0) - px[u];
                float dy = (c ? cy1 : cy0) - py[u];
                float dz = (c ? cz1 : cz0) - pz[u];
                float d2 = dx*dx + dy*dy + dz*dz;
                int dd = j - (ibn + c); dd = dd < 0 ? -dd : dd;
                if (dd <= 3) d2 = 1e30f;
                d2r[c][u] = d2;
                if (d2 < 144.0f)
                    atomicAdd(&hist[(c<<8) + (int)(d2*BSCALE)], 1u);
            }
        }
        __syncthreads();
        if (wv < 2) {   // scan (r6-r9 verified)
            unsigned h4[4]; unsigned s = 0;
            #pragma unroll
            for (int v = 0; v < 4; v++) { h4[v] = hist[(wv<<8) + lane*4 + v]; s += h4[v]; }
            unsigned inc = s;
            #pragma unroll
            for (int off = 1; off < 64; off <<= 1) {
                unsigned n = __shfl_up(inc, off, 64);
                if (lane >= off) inc += n;
            }
            unsigned tot = __shfl(inc, 63, 64);
            unsigned excl = inc - s;
            if (tot < 64u) {
                if (lane == 0) { sB[wv] = 255; sNeed[wv] = 64 - (int)tot; }
            } else if (excl < 64u && 64u <= inc) {
                unsigned cc = excl;
                #pragma unroll
                for (int v = 0; v < 4; v++) {
                    if (cc < 64u && 64u <= cc + h4[v]) { sB[wv] = lane*4+v; sNeed[wv] = 64 - (int)cc; }
                    cc += h4[v];
                }
            }
        }
        __syncthreads();
        #pragma unroll
        for (int u = 0; u < 8; u++) {   // pass 2 -> nbrL[0]
            int j = tid*8 + u;
            #pragma unroll
            for (int c = 0; c < 2; c++) {
                float d2 = d2r[c][u];
                int B = sB[c];
                if (d2 < 144.0f) {
                    int key = (int)(d2*BSCALE);
                    if (key < B) {
                        int pos = atomicAdd(&oPos[c], 1);
                        nbrL[(c<<6) + pos] = j;
                    } else if (key == B) {
                        int cc = atomicAdd(&cCnt[c], 1);
                        if (cc < 128) { cand_d2[(c<<7)+cc] = d2; cand_j[(c<<7)+cc] = j; }
                    }
                } else if (B == 255 && d2 < 1e29f) {
                    int t = atomicAdd(&fCnt[c], 1);
                    if (t < sNeed[c]) {
                        int pos = atomicAdd(&oPos[c], 1);
                        nbrL[(c<<6) + pos] = j;
                    }
                }
            }
        }
        __syncthreads();
        if (wv < 2) {   // boundary bin exact rank -> nbrL[0]
            int B = sB[wv];
            if (B != 255) {
                int cn = cCnt[wv]; if (cn > 128) cn = 128;
                int need = sNeed[wv];
                for (int ci = lane; ci < cn; ci += 64) {
                    float dv = cand_d2[(wv<<7)+ci]; int jv = cand_j[(wv<<7)+ci];
                    int rank = 0;
                    for (int x = 0; x < cn; x++) {
                        float dx2 = cand_d2[(wv<<7)+x]; int jx2 = cand_j[(wv<<7)+x];
                        rank += (dx2 < dv) || (dx2 == dv && jx2 < jv);
                    }
                    if (rank < need) {
                        int pos = atomicAdd(&oPos[wv], 1);
                        nbrL[(wv<<6) + pos] = jv;
                    }
                }
            }
        }
        __syncthreads();   // nbrL[0] complete
    }

    // ========================== PIPELINED MAIN LOOP =========================
    int cur = 0;
    for (int tile = blockIdx.x; tile < NTILES; tile += NBLOCKS) {
        const int b   = tile >> 10;
        const int tn  = tile + NBLOCKS;
        const bool hn = tn < NTILES;
        const int nxt = cur ^ 1;
        float rloc = 0.f;

        // ---- slot A: X build from nbrL[cur]; reset topk scratch for tn ----
        if (hn) {
            hist[tid] = 0u; hist[tid + 256] = 0u;
            if (tid < 2) { oPos[tid] = 0; cCnt[tid] = 0; fCnt[tid] = 0; }
        }
        {
            int c  = pl >> 6;
            int bi = (b << 11) + ((tile & 1023) << 1) + c;
            int j  = nbrL[cur*128 + pl];
            int rowj = (b << 11) + j;
            int si = seq[bi], sj = seq[rowj];
            const float4* ei = (const float4*)(emb + si*16 + half*8);
            const float4* ej = (const float4*)(emb + sj*16 + half*8);
            float4 eA0 = ei[0], eA1 = ei[1], eB0 = ej[0], eB1 = ej[1];
            int rb = pl*64;
            uint4 vA = make_uint4(pkbf(eA0.x,eA0.y), pkbf(eA0.z,eA0.w),
                                  pkbf(eA1.x,eA1.y), pkbf(eA1.z,eA1.w));
            uint4 vB = make_uint4(pkbf(eB0.x,eB0.y), pkbf(eB0.z,eB0.w),
                                  pkbf(eB1.x,eB1.y), pkbf(eB1.z,eB1.w));
            uint4 vP = make_uint4(pkbf(eA0.x*eB0.x, eA0.y*eB0.y),
                                  pkbf(eA0.z*eB0.z, eA0.w*eB0.w),
                                  pkbf(eA1.x*eB1.x, eA1.y*eB1.y),
                                  pkbf(eA1.z*eB1.z, eA1.w*eB1.w));
            *(uint4*)&Xs[rb + (((0|half)^s7p)<<3)] = vA;
            *(uint4*)&Xs[rb + (((2|half)^s7p)<<3)] = vB;
            *(uint4*)&Xs[rb + (((4|half)^s7p)<<3)] = vP;
            *(uint4*)&Xs[rb + (((6|half)^s7p)<<3)] = make_uint4(0u,0u,0u,0u);
            if (!half) {
                float dx = R[bi*3+0]-R[rowj*3+0];
                float dy = R[bi*3+1]-R[rowj*3+1];
                float dz = R[bi*3+2]-R[rowj*3+2];
                rloc = sqrtf(dx*dx + dy*dy + dz*dz + 1e-12f);
            }
        }
        __syncthreads();   // B: X ready, hist zeroed

        // ---- slot C: GEMM1 + topk pass1(tn) (loads hoisted above MFMAs) ----
        float4 f0, f1, f2, f3, f4, f5;
        float cx0=0, cy0=0, cz0=0, cx1=0, cy1=0, cz1=0;
        int ibn = 0;
        if (hn) {
            const float* Rbn = R + (((tn >> 10) << 11) * 3);
            ibn = (tn & 1023) << 1;
            const float4* rp = (const float4*)(Rbn + tid*24);
            f0=rp[0]; f1=rp[1]; f2=rp[2]; f3=rp[3]; f4=rp[4]; f5=rp[5];
            cx0 = Rbn[3*ibn+0]; cy0 = Rbn[3*ibn+1]; cz0 = Rbn[3*ibn+2];
            cx1 = Rbn[3*ibn+3]; cy1 = Rbn[3*ibn+4]; cz1 = Rbn[3*ibn+5];
        }
        #pragma unroll
        for (int nt = 0; nt < 8; nt++) {
            int row = nt*16 + l15;
            int s7 = l15 & 7;
            const unsigned short* xr = Xs + row*64;
            short8 x0 = *(const short8*)&xr[(( q    ^ s7) << 3)];
            short8 x1 = *(const short8*)&xr[(((4|q) ^ s7) << 3)];
            #pragma unroll
            for (int mtl = 0; mtl < 2; mtl++) {
                floatx4 acc = {b1v[mtl][0], b1v[mtl][1], b1v[mtl][2], b1v[mtl][3]};
                acc = __builtin_amdgcn_mfma_f32_16x16x32_bf16(w1f[mtl][0], x0, acc, 0, 0, 0);
                acc = __builtin_amdgcn_mfma_f32_16x16x32_bf16(w1f[mtl][1], x1, acc, 0, 0, 0);
                int chnk = (((2*wv + mtl)*2 + (q>>1)) ^ s7);
                *(uint2*)&Hs[row*128 + (chnk<<3) + ((q&1)<<2)] =
                    make_uint2(pkbf(fmaxf(acc[0],0.f), fmaxf(acc[1],0.f)),
                               pkbf(fmaxf(acc[2],0.f), fmaxf(acc[3],0.f)));
            }
        }
        if (hn) {
            float px[8], py[8], pz[8];
            px[0]=f0.x; py[0]=f0.y; pz[0]=f0.z;  px[1]=f0.w; py[1]=f1.x; pz[1]=f1.y;
            px[2]=f1.z; py[2]=f1.w; pz[2]=f2.x;  px[3]=f2.y; py[3]=f2.z; pz[3]=f2.w;
            px[4]=f3.x; py[4]=f3.y; pz[4]=f3.z;  px[5]=f3.w; py[5]=f4.x; pz[5]=f4.y;
            px[6]=f4.z; py[6]=f4.w; pz[6]=f5.x;  px[7]=f5.y; py[7]=f5.z; pz[7]=f5.w;
            #pragma unroll
            for (int u = 0; u < 8; u++) {
                int j = tid*8 + u;
                #pragma unroll
                for (int c = 0; c < 2; c++) {
                    float dx = (c ? cx1 : cx0) - px[u];
                    float dy = (c ? cy1 : cy0) - py[u];
                    float dz = (c ? cz1 : cz0) - pz[u];
                    float d2 = dx*dx + dy*dy + dz*dz;
                    int dd = j - (ibn + c); dd = dd < 0 ? -dd : dd;
                    if (dd <= 3) d2 = 1e30f;
                    d2r[c][u] = d2;
                    if (d2 < 144.0f)
                        atomicAdd(&hist[(c<<8) + (int)(d2*BSCALE)], 1u);
                }
            }
        }
        __syncthreads();   // D: H1 ready, hist(tn) complete

        // ---- slot E: GEMM2 (H1 -> packed H2 in regs) + scan(tn) ----
        uint2 h2p[8][2];
        #pragma unroll
        for (int nt = 0; nt < 8; nt++) {
            int row = nt*16 + l15;
            int s7 = l15 & 7;
            const unsigned short* hr = Hs + row*128;
            short8 hf0 = *(const short8*)&hr[(( q     ^ s7) << 3)];
            short8 hf1 = *(const short8*)&hr[((( 4|q) ^ s7) << 3)];
            short8 hf2 = *(const short8*)&hr[((( 8|q) ^ s7) << 3)];
            short8 hf3 = *(const short8*)&hr[(((12|q) ^ s7) << 3)];
            #pragma unroll
            for (int mtl = 0; mtl < 2; mtl++) {
                floatx4 acc = {b2v[mtl][0], b2v[mtl][1], b2v[mtl][2], b2v[mtl][3]};
                acc = __builtin_amdgcn_mfma_f32_16x16x32_bf16(w2f[mtl][0], hf0, acc, 0, 0, 0);
                acc = __builtin_amdgcn_mfma_f32_16x16x32_bf16(w2f[mtl][1], hf1, acc, 0, 0, 0);
                acc = __builtin_amdgcn_mfma_f32_16x16x32_bf16(w2f[mtl][2], hf2, acc, 0, 0, 0);
                acc = __builtin_amdgcn_mfma_f32_16x16x32_bf16(w2f[mtl][3], hf3, acc, 0, 0, 0);
                h2p[nt][mtl] = make_uint2(pkbf(fmaxf(acc[0],0.f), fmaxf(acc[1],0.f)),
                                          pkbf(fmaxf(acc[2],0.f), fmaxf(acc[3],0.f)));
            }
        }
        if (hn && wv < 2) {
            unsigned h4[4]; unsigned s = 0;
            #pragma unroll
            for (int v = 0; v < 4; v++) { h4[v] = hist[(wv<<8) + lane*4 + v]; s += h4[v]; }
            unsigned inc = s;
            #pragma unroll
            for (int off = 1; off < 64; off <<= 1) {
                unsigned n = __shfl_up(inc, off, 64);
                if (lane >= off) inc += n;
            }
            unsigned tot = __shfl(inc, 63, 64);
            unsigned excl = inc - s;
            if (tot < 64u) {
                if (lane == 0) { sB[wv] = 255; sNeed[wv] = 64 - (int)tot; }
            } else if (excl < 64u && 64u <= inc) {
                unsigned cc = excl;
                #pragma unroll
                for (int v = 0; v < 4; v++) {
                    if (cc < 64u && 64u <= cc + h4[v]) { sB[wv] = lane*4+v; sNeed[wv] = 64 - (int)cc; }
                    cc += h4[v];
                }
            }
        }
        __syncthreads();   // F: H1 reads done, scan done

        // ---- slot G: H2 writeback + topk pass2(tn) -> nbrL[nxt] ----
        #pragma unroll
        for (int nt = 0; nt < 8; nt++) {
            int row = nt*16 + l15;
            int s7 = l15 & 7;
            #pragma unroll
            for (int mtl = 0; mtl < 2; mtl++) {
                int chnk = (((2*wv + mtl)*2 + (q>>1)) ^ s7);
                *(uint2*)&Hs[row*128 + (chnk<<3) + ((q&1)<<2)] = h2p[nt][mtl];
            }
        }
        if (hn) {
            #pragma unroll
            for (int u = 0; u < 8; u++) {
                int j = tid*8 + u;
                #pragma unroll
                for (int c = 0; c < 2; c++) {
                    float d2 = d2r[c][u];
                    int B = sB[c];
                    if (d2 < 144.0f) {
                        int key = (int)(d2*BSCALE);
                        if (key < B) {
                            int pos = atomicAdd(&oPos[c], 1);
                            nbrL[nxt*128 + (c<<6) + pos] = j;
                        } else if (key == B) {
                            int cc = atomicAdd(&cCnt[c], 1);
                            if (cc < 128) { cand_d2[(c<<7)+cc] = d2; cand_j[(c<<7)+cc] = j; }
                        }
                    } else if (B == 255 && d2 < 1e29f) {
                        // <64 inside cutoff: fill with beyond-cutoff non-bonded
                        // pairs -- each contributes exactly 0 via the smoothstep
                        int t = atomicAdd(&fCnt[c], 1);
                        if (t < sNeed[c]) {
                            int pos = atomicAdd(&oPos[c], 1);
                            nbrL[nxt*128 + (c<<6) + pos] = j;
                        }
                    }
                }
            }
        }
        __syncthreads();   // H: H2 ready, pass2 done

        // ---- slot I: GEMM3 + epilogue + boundary rank(tn) ----
        float esum = 0.f;
        #pragma unroll
        for (int ntl = 0; ntl < 2; ntl++) {
            int nt = 2*wv + ntl;
            int row = nt*16 + l15;
            int s7 = l15 & 7;
            const unsigned short* hr = Hs + row*128;
            floatx4 a3 = {b3C[0], b3C[1], b3C[2], b3C[3]};
            #pragma unroll
            for (int kt = 0; kt < 4; kt++) {
                short8 hf = *(const short8*)&hr[((((kt<<2)|q) ^ s7) << 3)];
                a3 = __builtin_amdgcn_mfma_f32_16x16x32_bf16(w3f[kt], hf, a3, 0, 0, 0);
            }
            // pair p = 32wv+16ntl+l15; its r lives in lane 32ntl+2*l15 (r6-r9)
            float rr = __shfl(rloc, (ntl<<5) + 2*l15, 64);
            if (rr < 12.0f) {
                float att = 0.f;
                #pragma unroll
                for (int d = 0; d < 4; d++) {
                    if (q*4 + d < MRBF) {
                        float x = a3[d];
                        float sp = fmaxf(x, 0.f) + __logf(1.f + __expf(-fabsf(x)));
                        float df = rr - cen[d];
                        att += sp * __expf(-df*df*i2w[d]);
                    }
                }
                att += __shfl_xor(att, 16, 64);
                att += __shfl_xor(att, 32, 64);
                float t = fminf(fmaxf((rr - 10.f)*0.5f, 0.f), 1.f);
                float sw = 1.f - t*t*(3.f - 2.f*t);
                esum -= att * sw;   // 4x quad-replicated; x0.25 at flush
            }
        }
        if (hn && wv < 2) {
            int B = sB[wv];
            if (B != 255) {
                int cn = cCnt[wv]; if (cn > 128) cn = 128;
                int need = sNeed[wv];
                for (int ci = lane; ci < cn; ci += 64) {
                    float dv = cand_d2[(wv<<7)+ci]; int jv = cand_j[(wv<<7)+ci];
                    int rank = 0;
                    for (int x = 0; x < cn; x++) {
                        float dx2 = cand_d2[(wv<<7)+x]; int jx2 = cand_j[(wv<<7)+x];
                        rank += (dx2 < dv) || (dx2 == dv && jx2 < jv);
                    }
                    if (rank < need) {
                        int pos = atomicAdd(&oPos[wv], 1);
                        nbrL[nxt*128 + (wv<<6) + pos] = jv;
                    }
                }
            }
        }
        #pragma unroll
        for (int off = 1; off < 64; off <<= 1)
            esum += __shfl_xor(esum, off, 64);
        if (lane == 0) atomicAdd(&bacc[b], esum * 0.25f);
        __syncthreads();   // J: nbrL[nxt] complete, Hs reads done

        cur = nxt;
    }
    if (tid < BATCH) atomicAdd(&out[tid], bacc[tid]);
}

// ---------------------------------------------------------------------------
extern "C" void kernel_launch(void* const* d_in, const int* in_sizes, int n_in,
                              void* d_out, int out_size, void* d_ws, size_t ws_size,
                              hipStream_t stream) {
    const float* R       = (const float*)d_in[0];
    const int*   seq     = (const int*)  d_in[1];
    const float* emb     = (const float*)d_in[2];
    const float* W1      = (const float*)d_in[3];
    const float* b1      = (const float*)d_in[4];
    const float* W2      = (const float*)d_in[5];
    const float* b2      = (const float*)d_in[6];
    const float* W3      = (const float*)d_in[7];
    const float* b3      = (const float*)d_in[8];
    const float* centers = (const float*)d_in[9];
    const float* widths  = (const float*)d_in[10];
    float* out = (float*)d_out;

    hipMemsetAsync(d_out, 0, out_size * sizeof(float), stream);

    fused_kernel<<<NBLOCKS, 256, 0, stream>>>(R, seq, emb, W1, b1, W2, b2, W3, b3,
                                              centers, widths, out);
}

// Round 11
// 258.772 us; speedup vs baseline: 1.5163x; 1.5163x over previous
//
#include <hip/hip_runtime.h>
#include <math.h>

#define LSEQ 2048
#define KNB 64
#define BATCH 8
#define MRBF 7
#define NTILES 8192               // 2 rows per tile, 128 pairs
#define NBLOCKS 512               // 16 tiles per block exactly, 2 blocks/CU
#define BSCALE (255.0f/144.0f)

typedef __attribute__((ext_vector_type(8))) short short8;
typedef __attribute__((ext_vector_type(4))) float floatx4;

// RNE float->bf16 (cold path: weight setup)
__device__ __forceinline__ unsigned short f2bf(float f) {
    unsigned u = __float_as_uint(f);
    u += 0x7fffu + ((u >> 16) & 1u);
    return (unsigned short)(u >> 16);
}
// packed round-half-up bf16x2, 3 ops via v_perm (r4-r10 proven)
__device__ __forceinline__ unsigned pkbf(float a, float b) {
    return __builtin_amdgcn_perm(__float_as_uint(b) + 0x8000u,
                                 __float_as_uint(a) + 0x8000u, 0x07060302u);
}

// ---------------------------------------------------------------------------
// Fused kernel r11: 512-thread / 8-wave blocks; wave wv owns neuron tile wv.
// Rationale (r7 counters: 29k cyc wall vs ~5k issue/tile, 8 waves/CU): the
// kernel is latency-bound and register-bound. Widening the block HALVES
// per-wave weight registers (92 -> ~60 VGPR) and per-thread topk state, so
// __launch_bounds__(512,4) (=> 2 blocks/CU = 16 waves/CU, 2x r7) fits under
// the 128-VGPR cap WITHOUT spill -- unlike r8/r9/r10 which all added state.
// Same verified algorithm: exact histogram top-K + 3-GEMM MFMA MLP.
// Fragment layouts (r2/r4-r10 HW-verified, absmax=0):
//  A[m][k]: m=lane&15, k=quad*8+j | B[k][n]: n=lane&15, k=quad*8+j
//  D[r][c]: r=quad*4+reg, c=lane&15
// ---------------------------------------------------------------------------
__global__ __launch_bounds__(512, 4) void fused_kernel(
    const float* __restrict__ R, const int* __restrict__ seq,
    const float* __restrict__ emb,
    const float* __restrict__ W1, const float* __restrict__ b1,
    const float* __restrict__ W2, const float* __restrict__ b2,
    const float* __restrict__ W3, const float* __restrict__ b3,
    const float* __restrict__ centers, const float* __restrict__ widths,
    float* __restrict__ out)
{
    __shared__ __align__(16) unsigned short lds[24576];   // 48 KB: X + H
    unsigned short* Xs = lds;                 // [0,16384): X tile 128x64 bf16
    unsigned short* Hs = lds + 8192;          // [16384,49152): H1/H2 128x128
    // candidate store aliases Xs (X dead during topk; cand consumed in the
    // boundary phase, X written only after it):
    float* cand_d2 = (float*)lds;             // 2 x 128 f32, bytes [0,1024)
    int*   cand_j  = (int*)(lds + 512);       // 2 x 128 int, bytes [1024,2048)
    __shared__ int      nbrL[128];
    __shared__ unsigned hist[512];            // 2 rows x 256 bins (dedicated)
    __shared__ int sB[2], sNeed[2], oPos[2], cCnt[2], fCnt[2];
    __shared__ float bacc[BATCH];

    const int tid  = threadIdx.x;
    const int lane = tid & 63;
    const int wv   = tid >> 6;     // 0..7 = neuron tile
    const int l15  = lane & 15;
    const int q    = lane >> 4;

    // ---- persistent A-operand weight fragments (1 neuron tile per wave) ----
    short8 w1f[2], w2f[4], w3f[4];
    float b1v[4], b2v[4];
    {
        int m = wv*16 + l15;
        #pragma unroll
        for (int d = 0; d < 4; d++) {
            b1v[d] = b1[wv*16 + q*4 + d];
            b2v[d] = b2[wv*16 + q*4 + d];
        }
        #pragma unroll
        for (int kt = 0; kt < 2; kt++)
            #pragma unroll
            for (int jj = 0; jj < 8; jj++) {
                int k = kt*32 + q*8 + jj;
                w1f[kt][jj] = (short)((k < 48) ? f2bf(W1[k*128 + m]) : 0);
            }
        #pragma unroll
        for (int kt = 0; kt < 4; kt++)
            #pragma unroll
            for (int jj = 0; jj < 8; jj++) {
                int k = kt*32 + q*8 + jj;
                w2f[kt][jj] = (short)f2bf(W2[k*128 + m]);
            }
        #pragma unroll
        for (int kt = 0; kt < 4; kt++)
            #pragma unroll
            for (int jj = 0; jj < 8; jj++) {
                int k = kt*32 + q*8 + jj;
                w3f[kt][jj] = (short)((l15 < MRBF) ? f2bf(W3[k*MRBF + l15]) : 0);
            }
    }
    float b3C[4], cen[4], i2w[4];
    #pragma unroll
    for (int d = 0; d < 4; d++) {
        int rb = q*4 + d;
        bool ok = rb < MRBF;
        b3C[d] = ok ? b3[rb] : 0.f;
        cen[d] = ok ? centers[rb] : 0.f;
        float wd = ok ? widths[rb] : 1.f;
        i2w[d] = 0.5f / (wd*wd);
    }
    if (tid < BATCH) bacc[tid] = 0.f;

    const int pl = tid >> 2, qd = tid & 3;    // X build: 4 threads per pair
    const int s7p = pl & 7;
    float rloc = 0.f;

    for (int tile = blockIdx.x; tile < NTILES; tile += NBLOCKS) {
        const int b     = tile >> 10;
        const int ibase = (tile & 1023) << 1;
        const float* Rb = R + ((b << 11) * 3);

        // ================= TOPK PHASE (2 rows, 4 cands/thread) =============
        hist[tid & 511] = 0u;                 // 512 threads cover 512 bins
        if (tid < 2) { oPos[tid] = 0; cCnt[tid] = 0; fCnt[tid] = 0; }

        float px[4], py[4], pz[4];
        {
            const float4* rp = (const float4*)(Rb + tid*12);  // points tid*4..+3
            float4 f0 = rp[0], f1 = rp[1], f2 = rp[2];
            px[0]=f0.x; py[0]=f0.y; pz[0]=f0.z;
            px[1]=f0.w; py[1]=f1.x; pz[1]=f1.y;
            px[2]=f1.z; py[2]=f1.w; pz[2]=f2.x;
            px[3]=f2.y; py[3]=f2.z; pz[3]=f2.w;
        }
        float cx0 = Rb[3*ibase+0], cy0 = Rb[3*ibase+1], cz0 = Rb[3*ibase+2];
        float cx1 = Rb[3*ibase+3], cy1 = Rb[3*ibase+4], cz1 = Rb[3*ibase+5];
        __syncthreads();   // (1) hist zeros + counters visible

        // pass 1: d2 to registers, in-cutoff histogram. bonded -> 1e30
        // (excluded from cutoff AND fill); key 0..254 exact-monotone in d2;
        // beyond cutoff contributes exactly 0 (smoothstep) -> fill set.
        float d2r[2][4];
        #pragma unroll
        for (int u = 0; u < 4; u++) {
            int j = tid*4 + u;
            #pragma unroll
            for (int c = 0; c < 2; c++) {
                float dx = (c ? cx1 : cx0) - px[u];
                float dy = (c ? cy1 : cy0) - py[u];
                float dz = (c ? cz1 : cz0) - pz[u];
                float d2 = dx*dx + dy*dy + dz*dz;
                int dd = j - (ibase + c); dd = dd < 0 ? -dd : dd;
                if (dd <= 3) d2 = 1e30f;
                d2r[c][u] = d2;
                if (d2 < 144.0f)
                    atomicAdd(&hist[(c<<8) + (int)(d2*BSCALE)], 1u);
            }
        }
        __syncthreads();   // (2) hist complete

        // scan: wave 0 -> row 0, wave 1 -> row 1 (r6-r10 verified logic)
        if (wv < 2) {
            unsigned h4[4]; unsigned s = 0;
            #pragma unroll
            for (int v = 0; v < 4; v++) { h4[v] = hist[(wv<<8) + lane*4 + v]; s += h4[v]; }
            unsigned inc = s;
            #pragma unroll
            for (int off = 1; off < 64; off <<= 1) {
                unsigned n = __shfl_up(inc, off, 64);
                if (lane >= off) inc += n;
            }
            unsigned tot = __shfl(inc, 63, 64);
            unsigned excl = inc - s;
            if (tot < 64u) {
                if (lane == 0) { sB[wv] = 255; sNeed[wv] = 64 - (int)tot; }
            } else if (excl < 64u && 64u <= inc) {
                unsigned cc = excl;
                #pragma unroll
                for (int v = 0; v < 4; v++) {
                    if (cc < 64u && 64u <= cc + h4[v]) { sB[wv] = lane*4+v; sNeed[wv] = 64 - (int)cc; }
                    cc += h4[v];
                }
            }
        }
        __syncthreads();   // (3) sB/sNeed visible

        // pass 2: winners -> nbrL; boundary bin -> exact candidates; far fill
        #pragma unroll
        for (int u = 0; u < 4; u++) {
            int j = tid*4 + u;
            #pragma unroll
            for (int c = 0; c < 2; c++) {
                float d2 = d2r[c][u];
                int B = sB[c];
                if (d2 < 144.0f) {
                    int key = (int)(d2*BSCALE);
                    if (key < B) {
                        int pos = atomicAdd(&oPos[c], 1);
                        nbrL[(c<<6) + pos] = j;
                    } else if (key == B) {
                        int cc = atomicAdd(&cCnt[c], 1);
                        if (cc < 128) { cand_d2[(c<<7)+cc] = d2; cand_j[(c<<7)+cc] = j; }
                    }
                } else if (B == 255 && d2 < 1e29f) {
                    // <64 inside cutoff: fill with beyond-cutoff non-bonded
                    // pairs -- each contributes exactly 0 via the smoothstep
                    int t = atomicAdd(&fCnt[c], 1);
                    if (t < sNeed[c]) {
                        int pos = atomicAdd(&oPos[c], 1);
                        nbrL[(c<<6) + pos] = j;
                    }
                }
            }
        }
        __syncthreads();   // (4) pass2 done

        // boundary bin: exact (d2, j) rank; wave 0 -> row 0, wave 1 -> row 1
        if (wv < 2) {
            int B = sB[wv];
            if (B != 255) {
                int cn = cCnt[wv]; if (cn > 128) cn = 128;
                int need = sNeed[wv];
                for (int ci = lane; ci < cn; ci += 64) {
                    float dv = cand_d2[(wv<<7)+ci]; int jv = cand_j[(wv<<7)+ci];
                    int rank = 0;
                    for (int x = 0; x < cn; x++) {
                        float dx2 = cand_d2[(wv<<7)+x]; int jx2 = cand_j[(wv<<7)+x];
                        rank += (dx2 < dv) || (dx2 == dv && jx2 < jv);
                    }
                    if (rank < need) {
                        int pos = atomicAdd(&oPos[wv], 1);
                        nbrL[(wv<<6) + pos] = jv;
                    }
                }
            }
        }
        __syncthreads();   // (5) nbrL complete; cand reads done

        // ========= X BUILD: 4 threads/pair; partner vector via shfl ========
        // qd0 -> chunk0 (e_i[0:8]) + chunk4 (prod[0:8])
        // qd1 -> chunk1 (e_i[8:16]) + chunk5 (prod[8:16])
        // qd2 -> chunk2 (e_j[0:8]) + chunk6 (zeros)
        // qd3 -> chunk3 (e_j[8:16]) + chunk7 (zeros)
        {
            int c  = pl >> 6;
            int bi = (b << 11) + ibase + c;
            int j  = nbrL[pl];
            int rowj = (b << 11) + j;
            int si = seq[bi], sj = seq[rowj];
            const float* ep = emb + ((qd < 2) ? si : sj)*16 + (qd & 1)*8;
            float4 ea0 = *(const float4*)ep;
            float4 ea1 = *(const float4*)(ep + 4);
            // partner (tid^2): e_i half <-> e_j half of the same pair
            float4 pb0, pb1;
            pb0.x = __shfl_xor(ea0.x, 2, 64); pb0.y = __shfl_xor(ea0.y, 2, 64);
            pb0.z = __shfl_xor(ea0.z, 2, 64); pb0.w = __shfl_xor(ea0.w, 2, 64);
            pb1.x = __shfl_xor(ea1.x, 2, 64); pb1.y = __shfl_xor(ea1.y, 2, 64);
            pb1.z = __shfl_xor(ea1.z, 2, 64); pb1.w = __shfl_xor(ea1.w, 2, 64);
            int rb = pl*64;
            uint4 v0 = make_uint4(pkbf(ea0.x,ea0.y), pkbf(ea0.z,ea0.w),
                                  pkbf(ea1.x,ea1.y), pkbf(ea1.z,ea1.w));
            uint4 v1 = (qd < 2)
                ? make_uint4(pkbf(ea0.x*pb0.x, ea0.y*pb0.y),
                             pkbf(ea0.z*pb0.z, ea0.w*pb0.w),
                             pkbf(ea1.x*pb1.x, ea1.y*pb1.y),
                             pkbf(ea1.z*pb1.z, ea1.w*pb1.w))
                : make_uint4(0u, 0u, 0u, 0u);
            *(uint4*)&Xs[rb + ((qd       ^ s7p) << 3)] = v0;
            *(uint4*)&Xs[rb + (((qd + 4) ^ s7p) << 3)] = v1;
            if (qd == 0) {
                float dx = R[bi*3+0]-R[rowj*3+0];
                float dy = R[bi*3+1]-R[rowj*3+1];
                float dz = R[bi*3+2]-R[rowj*3+2];
                rloc = sqrtf(dx*dx + dy*dy + dz*dz + 1e-12f);
            }
        }
        __syncthreads();   // (6) X ready

        // ================= GEMM1: H1 = relu(W1^T X^T + b1) =================
        #pragma unroll
        for (int nt = 0; nt < 8; nt++) {
            int row = nt*16 + l15;
            int s7 = l15 & 7;
            const unsigned short* xr = Xs + row*64;
            short8 x0 = *(const short8*)&xr[(( q    ^ s7) << 3)];
            short8 x1 = *(const short8*)&xr[(((4|q) ^ s7) << 3)];
            floatx4 acc = {b1v[0], b1v[1], b1v[2], b1v[3]};
            acc = __builtin_amdgcn_mfma_f32_16x16x32_bf16(w1f[0], x0, acc, 0, 0, 0);
            acc = __builtin_amdgcn_mfma_f32_16x16x32_bf16(w1f[1], x1, acc, 0, 0, 0);
            int chnk = ((wv*2 + (q>>1)) ^ s7);
            *(uint2*)&Hs[row*128 + (chnk<<3) + ((q&1)<<2)] =
                make_uint2(pkbf(fmaxf(acc[0],0.f), fmaxf(acc[1],0.f)),
                           pkbf(fmaxf(acc[2],0.f), fmaxf(acc[3],0.f)));
        }
        __syncthreads();   // (7) H1 ready; X reads done

        // ---- GEMM2: read H1, hold packed H2 in 16 regs across barrier ----
        uint2 h2p[8];
        #pragma unroll
        for (int nt = 0; nt < 8; nt++) {
            int row = nt*16 + l15;
            int s7 = l15 & 7;
            const unsigned short* hr = Hs + row*128;
            short8 hf0 = *(const short8*)&hr[(( q     ^ s7) << 3)];
            short8 hf1 = *(const short8*)&hr[((( 4|q) ^ s7) << 3)];
            short8 hf2 = *(const short8*)&hr[((( 8|q) ^ s7) << 3)];
            short8 hf3 = *(const short8*)&hr[(((12|q) ^ s7) << 3)];
            floatx4 acc = {b2v[0], b2v[1], b2v[2], b2v[3]};
            acc = __builtin_amdgcn_mfma_f32_16x16x32_bf16(w2f[0], hf0, acc, 0, 0, 0);
            acc = __builtin_amdgcn_mfma_f32_16x16x32_bf16(w2f[1], hf1, acc, 0, 0, 0);
            acc = __builtin_amdgcn_mfma_f32_16x16x32_bf16(w2f[2], hf2, acc, 0, 0, 0);
            acc = __builtin_amdgcn_mfma_f32_16x16x32_bf16(w2f[3], hf3, acc, 0, 0, 0);
            h2p[nt] = make_uint2(pkbf(fmaxf(acc[0],0.f), fmaxf(acc[1],0.f)),
                                 pkbf(fmaxf(acc[2],0.f), fmaxf(acc[3],0.f)));
        }
        __syncthreads();   // (8) all H1 reads complete
        #pragma unroll
        for (int nt = 0; nt < 8; nt++) {
            int row = nt*16 + l15;
            int s7 = l15 & 7;
            int chnk = ((wv*2 + (q>>1)) ^ s7);
            *(uint2*)&Hs[row*128 + (chnk<<3) + ((q&1)<<2)] = h2p[nt];
        }
        __syncthreads();   // (9) H2 ready

        // ====== GEMM3 (W3^T H2^T) + epilogue; wave wv owns pair-tile wv ====
        float esum = 0.f;
        {
            int row = wv*16 + l15;
            int s7 = l15 & 7;
            const unsigned short* hr = Hs + row*128;
            floatx4 a3 = {b3C[0], b3C[1], b3C[2], b3C[3]};
            #pragma unroll
            for (int kt = 0; kt < 4; kt++) {
                short8 hf = *(const short8*)&hr[((((kt<<2)|q) ^ s7) << 3)];
                a3 = __builtin_amdgcn_mfma_f32_16x16x32_bf16(w3f[kt], hf, a3, 0, 0, 0);
            }
            // pair p = wv*16 + l15; its rloc lives in lane 4*l15 of wave wv
            float rr = __shfl(rloc, 4*l15, 64);
            if (rr < 12.0f) {
                float att = 0.f;
                #pragma unroll
                for (int d = 0; d < 4; d++) {
                    if (q*4 + d < MRBF) {
                        float x = a3[d];
                        float sp = fmaxf(x, 0.f) + __logf(1.f + __expf(-fabsf(x)));
                        float df = rr - cen[d];
                        att += sp * __expf(-df*df*i2w[d]);
                    }
                }
                att += __shfl_xor(att, 16, 64);
                att += __shfl_xor(att, 32, 64);
                float t = fminf(fmaxf((rr - 10.f)*0.5f, 0.f), 1.f);
                float sw = 1.f - t*t*(3.f - 2.f*t);
                esum -= att * sw;   // 4x quad-replicated; x0.25 at flush
            }
        }
        #pragma unroll
        for (int off = 1; off < 64; off <<= 1)
            esum += __shfl_xor(esum, off, 64);
        if (lane == 0) atomicAdd(&bacc[b], esum * 0.25f);
        // next iteration starts with hist zeroing (dedicated region) and
        // counter init; the (1) barrier fences them before use. GEMM3's Hs
        // reads are fenced from the next H-write by barriers (1)-(7).
    }
    __syncthreads();
    if (tid < BATCH) atomicAdd(&out[tid], bacc[tid]);
}

// ---------------------------------------------------------------------------
extern "C" void kernel_launch(void* const* d_in, const int* in_sizes, int n_in,
                              void* d_out, int out_size, void* d_ws, size_t ws_size,
                              hipStream_t stream) {
    const float* R       = (const float*)d_in[0];
    const int*   seq     = (const int*)  d_in[1];
    const float* emb     = (const float*)d_in[2];
    const float* W1      = (const float*)d_in[3];
    const float* b1      = (const float*)d_in[4];
    const float* W2      = (const float*)d_in[5];
    const float* b2      = (const float*)d_in[6];
    const float* W3      = (const float*)d_in[7];
    const float* b3      = (const float*)d_in[8];
    const float* centers = (const float*)d_in[9];
    const float* widths  = (const float*)d_in[10];
    float* out = (float*)d_out;

    hipMemsetAsync(d_out, 0, out_size * sizeof(float), stream);

    fused_kernel<<<NBLOCKS, 512, 0, stream>>>(R, seq, emb, W1, b1, W2, b2, W3, b3,
                                              centers, widths, out);
}